// Round 1
// baseline (6701.220 us; speedup 1.0000x reference)
//
#include <hip/hip_runtime.h>
#include <hip/hip_bf16.h>

#define HW2D 65536
#define NPIX 524288   // 8 * 65536
#define NB 8
#define WDIM 32
#define CSRC 42
#define NSTEPS 16

typedef __hip_bfloat16 bf16;

__device__ __forceinline__ float bf2f(bf16 v){ return __bfloat162float(v); }
__device__ __forceinline__ bf16 f2bf(float v){ return __float2bfloat16(v); }

__device__ __forceinline__ float fast_tanh(float z){
  float az = fabsf(z);
  float e = __expf(2.0f*az);
  float t = 1.0f - 2.0f/(e+1.0f);
  return copysignf(t, z);
}
__device__ __forceinline__ float fast_sigmoid(float z){
  return 1.0f/(1.0f + __expf(-z));
}

// accum layout: [0..15] per-step diff2 sums, [16] norm sum, [17] pw sum,
// [18] sat count, [19] leak count, [20] cos_a, [21] sin_a, [22] decay
__global__ void k_prep(const float* angle, const float* decay_logit, float* accum){
  int t = threadIdx.x;
  if (t < 20) accum[t] = 0.0f;
  if (t == 0){
    float ang = tanhf(angle[0])*0.02f;
    accum[20] = cosf(ang);
    accum[21] = sinf(ang);
    accum[22] = 0.95f + 0.05f/(1.0f+expf(-decay_logit[0]));
  }
}

// w_up (32,42,3,3) -> w_t[(k*9+dy*3+dx)*32 + c]
__global__ void k_transpose(const float* __restrict__ w_up, float* __restrict__ w_t){
  int i = blockIdx.x*256 + threadIdx.x;
  if (i < 32*CSRC*9){
    int c = i / (CSRC*9);
    int k9 = i - c*(CSRC*9);
    w_t[k9*32 + c] = w_up[i];
  }
}

__global__ void k_init(const float* __restrict__ x, const float* __restrict__ w_in,
                       const float* __restrict__ b_in,
                       float* __restrict__ sr, float* __restrict__ si,
                       float* __restrict__ fr, float* __restrict__ fi,
                       bf16* __restrict__ hh, float* accum){
  int tid = threadIdx.x;
  int p = blockIdx.x*256 + tid;
  int b = p >> 16, rem = p & 65535;
  const float* xb = x + (size_t)b*6*HW2D;
  float wall = xb[rem];
  float fre = 1.0f - wall;
  float s_r = xb[HW2D + rem]*fre;
  float s_i = xb[2*HW2D + rem]*fre;
  sr[p]=s_r; si[p]=s_i; fr[p]=s_r; fi[p]=s_i;
  float src10[10];
  src10[0]=wall;
  #pragma unroll
  for (int c=1;c<6;c++) src10[c]=xb[c*HW2D+rem];
  src10[6]=s_r; src10[7]=s_i; src10[8]=s_r; src10[9]=s_i;
  bf16* hb = hh + (size_t)b*WDIM*HW2D + rem;
  #pragma unroll
  for (int c=0;c<32;c++){
    float a = b_in[c];
    #pragma unroll
    for (int k=0;k<10;k++) a += w_in[c*10+k]*src10[k];
    hb[(size_t)c*HW2D] = f2bf(fast_tanh(a)*fre);
  }
  // state0 norm contribution
  float v = sqrtf(s_r*s_r + s_i*s_i);
  #pragma unroll
  for (int off=32; off>0; off>>=1) v += __shfl_down(v, off);
  __shared__ float red[4];
  int wid = tid >> 6;
  if ((tid&63)==0) red[wid] = v;
  __syncthreads();
  if (tid==0) atomicAdd(&accum[16], red[0]+red[1]+red[2]+red[3]);
}

__global__ void k_step_a(const float* __restrict__ x, const bf16* __restrict__ hh,
                         const float* __restrict__ sro, const float* __restrict__ sio,
                         const float* __restrict__ fro, const float* __restrict__ fio,
                         float* __restrict__ srn, float* __restrict__ sinew,
                         float* __restrict__ frn, float* __restrict__ fin,
                         const float* __restrict__ w_gate, const float* __restrict__ b_gate,
                         float* accum, int step){
  int tid = threadIdx.x;
  int p = blockIdx.x*256 + tid;
  int b = p >> 16, rem = p & 65535;
  int y = rem >> 8, xw = rem & 255;
  const float* xb = x + (size_t)b*6*HW2D;
  float wall = xb[rem];
  float fre = 1.0f - wall;
  float incr=0.0f, inci=0.0f;
  if (y>0)   { incr += fro[p-256]; inci += fio[p-256]; }
  if (y<255) { incr += fro[p+256]; inci += fio[p+256]; }
  if (xw>0)  { incr += fro[p-1];   inci += fio[p-1];   }
  if (xw<255){ incr += fro[p+1];   inci += fio[p+1];   }
  if (step==8){ incr += xb[3*HW2D+rem]; inci += xb[4*HW2D+rem]; }
  float s_r = sro[p], s_i = sio[p], f_r = fro[p], f_i = fio[p];
  // gate conv (42 ch)
  float a = b_gate[0];
  const bf16* hb = hh + (size_t)b*WDIM*HW2D + rem;
  #pragma unroll
  for (int c=0;c<32;c++) a += w_gate[c]*bf2f(hb[(size_t)c*HW2D]);
  a += w_gate[32]*wall;
  #pragma unroll
  for (int c=1;c<6;c++) a += w_gate[32+c]*xb[c*HW2D+rem];
  a += w_gate[38]*s_r + w_gate[39]*s_i + w_gate[40]*f_r + w_gate[41]*f_i;
  float g = 0.998f + 0.002f*fast_sigmoid(a);
  incr *= g; inci *= g;
  float ca = accum[20], sa = accum[21], dec = accum[22];
  float rr = incr*ca - inci*sa;
  float ri = incr*sa + inci*ca;
  incr = rr*fre; inci = ri*fre;
  float mag = sqrtf(incr*incr + inci*inci + 1e-8f);
  float sc = fminf(2.0f/mag, 1.0f);
  incr *= sc; inci *= sc;
  float pw = (fabsf(incr)+fabsf(inci))*wall;
  float nr = dec*s_r + incr, ni = dec*s_i + inci;
  mag = sqrtf(nr*nr+ni*ni+1e-8f);
  sc = fminf(2.0f/mag, 1.0f);
  nr = nr*sc*fre; ni = ni*sc*fre;
  frn[p]=incr; fin[p]=inci; srn[p]=nr; sinew[p]=ni;
  float d2 = (nr-s_r)*(nr-s_r)+(ni-s_i)*(ni-s_i);
  float nrm = sqrtf(nr*nr+ni*ni);
  #pragma unroll
  for (int off=32; off>0; off>>=1){
    d2  += __shfl_down(d2, off);
    nrm += __shfl_down(nrm, off);
    pw  += __shfl_down(pw, off);
  }
  __shared__ float red[3][4];
  int wid = tid >> 6;
  if ((tid&63)==0){ red[0][wid]=d2; red[1][wid]=nrm; red[2][wid]=pw; }
  __syncthreads();
  if (tid==0){
    atomicAdd(&accum[step-1], red[0][0]+red[0][1]+red[0][2]+red[0][3]);
    atomicAdd(&accum[16],     red[1][0]+red[1][1]+red[1][2]+red[1][3]);
    atomicAdd(&accum[17],     red[2][0]+red[2][1]+red[2][2]+red[2][3]);
  }
}

__global__ __launch_bounds__(256) void k_step_b(const float* __restrict__ x,
    const bf16* __restrict__ hho, bf16* __restrict__ hhn,
    const float* __restrict__ sro, const float* __restrict__ sio,
    const float* __restrict__ fro, const float* __restrict__ fio,
    const float* __restrict__ w_t, const float* __restrict__ b_up){
  __shared__ float st[CSRC][18][19];
  int b = blockIdx.z;
  int tx = threadIdx.x, ty = threadIdx.y;
  int tid = ty*16+tx;
  int gx0 = blockIdx.x*16 - 1, gy0 = blockIdx.y*16 - 1;
  for (int i = tid; i < CSRC*324; i += 256){
    int k = i / 324;
    int r = i - k*324;
    int yy = r / 18, xx = r - yy*18;
    int gy = gy0+yy, gx = gx0+xx;
    float v = 0.0f;
    if ((unsigned)gy < 256u && (unsigned)gx < 256u){
      int rem = (gy<<8)+gx;
      if (k < 32)      v = bf2f(hho[((size_t)b*32+k)*HW2D + rem]);
      else if (k < 38) v = x[((size_t)b*6 + (k-32))*HW2D + rem];
      else if (k==38)  v = sro[(size_t)b*HW2D+rem];
      else if (k==39)  v = sio[(size_t)b*HW2D+rem];
      else if (k==40)  v = fro[(size_t)b*HW2D+rem];
      else             v = fio[(size_t)b*HW2D+rem];
    }
    st[k][yy][xx] = v;
  }
  __syncthreads();
  float acc[32];
  #pragma unroll
  for (int c=0;c<32;c++) acc[c] = b_up[c];
  for (int k=0;k<CSRC;k++){
    #pragma unroll
    for (int dy=0;dy<3;dy++){
      #pragma unroll
      for (int dx=0;dx<3;dx++){
        float v = st[k][ty+dy][tx+dx];
        const float* wr = w_t + ((k*9+dy*3+dx)<<5);
        #pragma unroll
        for (int c=0;c<32;c++) acc[c] += v*wr[c];
      }
    }
  }
  float fre = 1.0f - st[32][ty+1][tx+1];
  int rem = ((gy0+1+ty)<<8) + (gx0+1+tx);
  bf16* hn = hhn + (size_t)b*32*HW2D + rem;
  #pragma unroll
  for (int c=0;c<32;c++){
    float h = fast_tanh(0.8f*st[c][ty+1][tx+1] + acc[c])*fre;
    hn[(size_t)c*HW2D] = f2bf(h);
  }
}

__global__ void k_tail(const float* __restrict__ x, const float* __restrict__ sr,
                       const float* __restrict__ si, float* accum){
  int tid = threadIdx.x;
  int p = blockIdx.x*256 + tid;
  int b = p >> 16, rem = p & 65535;
  float wall = x[(size_t)b*6*HW2D + rem];
  float vr = sr[p], vi = si[p];
  float sat = (fabsf(vr)>4.0f ? 1.0f:0.0f) + (fabsf(vi)>4.0f ? 1.0f:0.0f);
  float nrm = sqrtf(vr*vr+vi*vi);
  float leak = (nrm>0.5f && wall>0.5f) ? 1.0f : 0.0f;
  #pragma unroll
  for (int off=32; off>0; off>>=1){
    sat  += __shfl_down(sat, off);
    leak += __shfl_down(leak, off);
  }
  __shared__ float red[2][4];
  int wid = tid >> 6;
  if ((tid&63)==0){ red[0][wid]=sat; red[1][wid]=leak; }
  __syncthreads();
  if (tid==0){
    atomicAdd(&accum[18], red[0][0]+red[0][1]+red[0][2]+red[0][3]);
    atomicAdd(&accum[19], red[1][0]+red[1][1]+red[1][2]+red[1][3]);
  }
}

__global__ void k_final(const float* __restrict__ sr, const float* __restrict__ si,
                        const int* __restrict__ target, const float* __restrict__ accum,
                        float* __restrict__ out){
  int t = threadIdx.x;
  if (t < 8){
    int ty = target[2*t], tx = target[2*t+1];
    int p = (t<<16) + (ty<<8) + tx;
    float vr = sr[p], vi = si[p];
    float mag = sqrtf(vr*vr+vi*vi+1e-8f);
    out[t*9] = (0.35f - mag)*12.0f;
    #pragma unroll
    for (int k=0;k<8;k++){
      float th = 6.283185307179586f * (float)k / 8.0f;
      out[t*9+1+k] = (vr*cosf(th)+vi*sinf(th) - 0.35f)*12.0f;
    }
  }
  if (t == 8){
    float d = 0.0f;
    for (int s=0;s<16;s++) d += sqrtf(accum[s]/1048576.0f);
    out[72] = d/16.0f;
    out[73] = accum[16]/8912896.0f;    // 17 * 524288
    out[74] = accum[18]/1048576.0f;
    out[75] = accum[17]/(524288.0f*16.0f);
    out[76] = accum[19]/524288.0f;
  }
}

extern "C" void kernel_launch(void* const* d_in, const int* in_sizes, int n_in,
                              void* d_out, int out_size, void* d_ws, size_t ws_size,
                              hipStream_t stream) {
  const float* x          = (const float*)d_in[0];
  const int*   target     = (const int*)  d_in[1];
  const float* w_in       = (const float*)d_in[2];
  const float* b_in       = (const float*)d_in[3];
  const float* w_up       = (const float*)d_in[4];
  const float* b_up       = (const float*)d_in[5];
  const float* w_gate     = (const float*)d_in[6];
  const float* b_gate     = (const float*)d_in[7];
  const float* angle      = (const float*)d_in[8];
  const float* decay_l    = (const float*)d_in[9];
  float* out = (float*)d_out;

  char* ws = (char*)d_ws;
  size_t off = 0;
  bf16* hh0 = (bf16*)(ws+off); off += (size_t)NB*WDIM*HW2D*sizeof(bf16);
  bf16* hh1 = (bf16*)(ws+off); off += (size_t)NB*WDIM*HW2D*sizeof(bf16);
  float* sr0 = (float*)(ws+off); off += (size_t)NPIX*4;
  float* si0 = (float*)(ws+off); off += (size_t)NPIX*4;
  float* fr0 = (float*)(ws+off); off += (size_t)NPIX*4;
  float* fi0 = (float*)(ws+off); off += (size_t)NPIX*4;
  float* sr1 = (float*)(ws+off); off += (size_t)NPIX*4;
  float* si1 = (float*)(ws+off); off += (size_t)NPIX*4;
  float* fr1 = (float*)(ws+off); off += (size_t)NPIX*4;
  float* fi1 = (float*)(ws+off); off += (size_t)NPIX*4;
  float* w_t = (float*)(ws+off); off += (size_t)32*CSRC*9*4;
  float* accum = (float*)(ws+off); off += 32*4;

  k_prep<<<1,32,0,stream>>>(angle, decay_l, accum);
  k_transpose<<<(32*CSRC*9+255)/256,256,0,stream>>>(w_up, w_t);
  k_init<<<NPIX/256,256,0,stream>>>(x, w_in, b_in, sr0, si0, fr0, fi0, hh0, accum);

  bf16 *hho=hh0, *hhn=hh1;
  float *sro=sr0,*sio=si0,*fro=fr0,*fio=fi0;
  float *srn=sr1,*sinew=si1,*frn=fr1,*fin=fi1;
  for (int t=1;t<=NSTEPS;t++){
    k_step_a<<<NPIX/256,256,0,stream>>>(x, hho, sro,sio,fro,fio, srn,sinew,frn,fin,
                                        w_gate, b_gate, accum, t);
    k_step_b<<<dim3(16,16,8),dim3(16,16),0,stream>>>(x, hho, hhn, sro,sio,fro,fio, w_t, b_up);
    bf16* th_=hho; hho=hhn; hhn=th_;
    float* tp;
    tp=sro; sro=srn; srn=tp;
    tp=sio; sio=sinew; sinew=tp;
    tp=fro; fro=frn; frn=tp;
    tp=fio; fio=fin; fin=tp;
  }
  k_tail<<<NPIX/256,256,0,stream>>>(x, sro, sio, accum);
  k_final<<<1,64,0,stream>>>(sro, sio, target, accum, out);
}

// Round 2
// 1788.194 us; speedup vs baseline: 3.7475x; 3.7475x over previous
//
#include <hip/hip_runtime.h>
#include <hip/hip_bf16.h>

#define HW2D 65536
#define NPIX 524288   // 8 * 65536
#define NB 8
#define PW 258
#define PP 66564      // 258*258
#define NSTEPS 16

typedef __hip_bfloat16 bf16;
typedef __attribute__((ext_vector_type(8))) short short8;
typedef __attribute__((ext_vector_type(4))) float f32x4;

__device__ __forceinline__ float bf2f(bf16 v){ return __bfloat162float(v); }
__device__ __forceinline__ bf16 f2bf(float v){ return __float2bfloat16(v); }
__device__ __forceinline__ float bfu(unsigned short u){
  unsigned int t = ((unsigned int)u) << 16; return __uint_as_float(t);
}
__device__ __forceinline__ unsigned short f2bfu(float v){
  bf16 h = __float2bfloat16(v); return *(unsigned short*)&h;
}

__device__ __forceinline__ float fast_tanh(float z){
  float az = fabsf(z);
  float e = __expf(2.0f*az);
  float t = 1.0f - 2.0f/(e+1.0f);
  return copysignf(t, z);
}
__device__ __forceinline__ float fast_sigmoid(float z){
  return 1.0f/(1.0f + __expf(-z));
}

// accum: [0..15] per-step diff2, [16] norm, [17] pw, [18] sat, [19] leak,
// [20] cos_a, [21] sin_a, [22] decay
__global__ void k_prep(const float* angle, const float* decay_logit, float* accum){
  int t = threadIdx.x;
  if (t < 20) accum[t] = 0.0f;
  if (t == 0){
    float ang = tanhf(angle[0])*0.02f;
    accum[20] = cosf(ang);
    accum[21] = sinf(ang);
    accum[22] = 0.95f + 0.05f/(1.0f+expf(-decay_logit[0]));
  }
}

// WB[((n*14+s)*64+lane)*8+j] : per-lane B fragments, bf16.
// seg1 (s=0..8): tap=s, src ch = (lane>>4)*8+j  (hh channels 0..31)
// seg2 (s=9..13): s2=s-9; tap=2*s2+((lane>>4)>>1); t=((lane>>4)&1)*8+j
//   tail map: t<4 -> src 38+t (s_r,s_i,f_r,f_i); 4<=t<10 -> src 32+(t-4) (x); else 0
__global__ void k_wprep(const float* __restrict__ w_up, bf16* __restrict__ WB){
  int idx = blockIdx.x*256 + threadIdx.x;
  if (idx >= 14336) return;
  int j = idx & 7;
  int lane = (idx >> 3) & 63;
  int s = (idx >> 9) % 14;
  int n = idx / 7168;
  int oc = n*16 + (lane & 15);
  int g = lane >> 4;
  float w = 0.0f;
  if (s < 9){
    int ch = g*8 + j;
    int dy = s/3, dx = s%3;
    w = w_up[((oc*42 + ch)*3 + dy)*3 + dx];
  } else {
    int s2 = s - 9;
    int tap = 2*s2 + (g>>1);
    int t = (g&1)*8 + j;
    if (tap <= 8 && t < 10){
      int src = (t < 4) ? (38 + t) : (32 + (t-4));
      int dy = tap/3, dx = tap%3;
      w = w_up[((oc*42 + src)*3 + dy)*3 + dx];
    }
  }
  WB[idx] = f2bf(w);
}

__global__ void k_border(bf16* HH0, bf16* HH1, bf16* TAIL){
  int i = blockIdx.x*256 + threadIdx.x;
  if (i >= NB*PP) return;
  int pp_ = i % PP;
  int r = pp_ / PW, c = pp_ % PW;
  if (r != 0 && r != 257 && c != 0 && c != 257) return;
  short8 z = (short8){0,0,0,0,0,0,0,0};
  short8* h0 = (short8*)HH0 + (size_t)i*4;
  short8* h1 = (short8*)HH1 + (size_t)i*4;
  short8* tl = (short8*)TAIL + (size_t)i*2;
  h0[0]=z; h0[1]=z; h0[2]=z; h0[3]=z;
  h1[0]=z; h1[1]=z; h1[2]=z; h1[3]=z;
  tl[0]=z; tl[1]=z;
}

__global__ void k_init(const float* __restrict__ x, const float* __restrict__ w_in,
                       const float* __restrict__ b_in,
                       float* __restrict__ sr, float* __restrict__ si,
                       float* __restrict__ fr, float* __restrict__ fi,
                       bf16* __restrict__ HH0, bf16* __restrict__ TAIL, float* accum){
  int tid = threadIdx.x;
  int p = blockIdx.x*256 + tid;
  int b = p >> 16, rem = p & 65535;
  int y = rem >> 8, xc = rem & 255;
  const float* xb = x + (size_t)b*6*HW2D;
  float wall = xb[rem];
  float fre = 1.0f - wall;
  float s_r = xb[HW2D + rem]*fre;
  float s_i = xb[2*HW2D + rem]*fre;
  sr[p]=s_r; si[p]=s_i; fr[p]=s_r; fi[p]=s_i;
  float src10[10];
  src10[0]=wall;
  #pragma unroll
  for (int c=1;c<6;c++) src10[c]=xb[c*HW2D+rem];
  src10[6]=s_r; src10[7]=s_i; src10[8]=s_r; src10[9]=s_i;
  size_t padpix = (size_t)b*PP + (y+1)*PW + (xc+1);
  unsigned short hv[32];
  #pragma unroll
  for (int c=0;c<32;c++){
    float a = b_in[c];
    #pragma unroll
    for (int k=0;k<10;k++) a += w_in[c*10+k]*src10[k];
    hv[c] = f2bfu(fast_tanh(a)*fre);
  }
  short8* hrec = (short8*)HH0 + padpix*4;
  #pragma unroll
  for (int q=0;q<4;q++){
    short8 v;
    #pragma unroll
    for (int j=0;j<8;j++) v[j] = (short)hv[q*8+j];
    hrec[q] = v;
  }
  unsigned short tv[16];
  tv[0]=f2bfu(s_r); tv[1]=f2bfu(s_i); tv[2]=f2bfu(s_r); tv[3]=f2bfu(s_i);
  #pragma unroll
  for (int c=0;c<6;c++) tv[4+c] = f2bfu(src10[c]);
  #pragma unroll
  for (int c=10;c<16;c++) tv[c] = 0;
  short8* trec = (short8*)TAIL + padpix*2;
  #pragma unroll
  for (int q=0;q<2;q++){
    short8 v;
    #pragma unroll
    for (int j=0;j<8;j++) v[j] = (short)tv[q*8+j];
    trec[q] = v;
  }
  float v = sqrtf(s_r*s_r + s_i*s_i);
  #pragma unroll
  for (int off=32; off>0; off>>=1) v += __shfl_down(v, off);
  __shared__ float red[4];
  int wid = tid >> 6;
  if ((tid&63)==0) red[wid] = v;
  __syncthreads();
  if (tid==0) atomicAdd(&accum[16], red[0]+red[1]+red[2]+red[3]);
}

// MFMA implicit-GEMM 3x3 conv: one block per (row, batch); 4 waves x 64 px.
__global__ __launch_bounds__(256) void k_conv(
    const bf16* __restrict__ HHo, bf16* __restrict__ HHn,
    const bf16* __restrict__ TAIL, const bf16* __restrict__ WB,
    const float* __restrict__ x, const float* __restrict__ b_up){
  int y = blockIdx.x, b = blockIdx.y;
  int tid = threadIdx.x;
  int wv = tid >> 6, lane = tid & 63;
  int r_ = lane & 15, g = lane >> 4;
  int bbase = b*PP;
  int rowbase = (y+1)*PW + 1;
  int pix[4];
  #pragma unroll
  for (int mt=0;mt<4;mt++) pix[mt] = bbase + rowbase + wv*64 + mt*16 + r_;
  f32x4 acc[4][2];
  #pragma unroll
  for (int mt=0;mt<4;mt++){
    acc[mt][0] = (f32x4){0.f,0.f,0.f,0.f};
    acc[mt][1] = (f32x4){0.f,0.f,0.f,0.f};
  }
  const short8* HH8 = (const short8*)HHo;
  const short8* T8  = (const short8*)TAIL;
  const short8* wb  = (const short8*)WB;

  // seg1: 9 taps x 32 hh channels
  #pragma unroll
  for (int s=0;s<9;s++){
    const int off = (s/3 - 1)*PW + (s%3 - 1);
    short8 b0 = wb[s*64 + lane];
    short8 b1 = wb[(14+s)*64 + lane];
    #pragma unroll
    for (int mt=0;mt<4;mt++){
      short8 a = HH8[(size_t)(pix[mt]+off)*4 + g];
      acc[mt][0] = __builtin_amdgcn_mfma_f32_16x16x32_bf16(a, b0, acc[mt][0], 0,0,0);
      acc[mt][1] = __builtin_amdgcn_mfma_f32_16x16x32_bf16(a, b1, acc[mt][1], 0,0,0);
    }
  }
  // seg2: 5 steps x (2 taps x 16 tail channels), tap 9 = zero border
  #pragma unroll
  for (int s2=0;s2<5;s2++){
    int s = 9+s2;
    short8 b0 = wb[s*64 + lane];
    short8 b1 = wb[(14+s)*64 + lane];
    const int tA = 2*s2, tB = 2*s2+1;
    const int offA = (tA/3 - 1)*PW + (tA%3 - 1);
    const int offB = (tB <= 8) ? ((tB/3 - 1)*PW + (tB%3 - 1)) : 0;
    bool hiB = (g >= 2);
    #pragma unroll
    for (int mt=0;mt<4;mt++){
      int tp;
      if (tB <= 8) tp = pix[mt] + (hiB ? offB : offA);
      else         tp = hiB ? bbase : (pix[mt] + offA);
      short8 a = T8[(size_t)tp*2 + (g&1)];
      acc[mt][0] = __builtin_amdgcn_mfma_f32_16x16x32_bf16(a, b0, acc[mt][0], 0,0,0);
      acc[mt][1] = __builtin_amdgcn_mfma_f32_16x16x32_bf16(a, b1, acc[mt][1], 0,0,0);
    }
  }
  // epilogue: hh_new = tanh(0.8*hh_old + acc + bias) * free
  const float* xw = x + (size_t)b*6*HW2D + y*256;
  float bias0 = b_up[r_], bias1 = b_up[16 + r_];
  #pragma unroll
  for (int mt=0;mt<4;mt++){
    #pragma unroll
    for (int i=0;i<4;i++){
      int px = wv*64 + mt*16 + g*4 + i;
      float fre = 1.0f - xw[px];
      size_t hof = (size_t)(bbase + rowbase + px)*32;
      float h0 = bf2f(HHo[hof + r_]);
      float h1 = bf2f(HHo[hof + 16 + r_]);
      HHn[hof + r_]      = f2bf(fast_tanh(0.8f*h0 + acc[mt][0][i] + bias0)*fre);
      HHn[hof + 16 + r_] = f2bf(fast_tanh(0.8f*h1 + acc[mt][1][i] + bias1)*fre);
    }
  }
}

__global__ void k_step_a(const float* __restrict__ x, const bf16* __restrict__ HH,
                         bf16* __restrict__ TAIL,
                         const float* __restrict__ sro, const float* __restrict__ sio,
                         const float* __restrict__ fro, const float* __restrict__ fio,
                         float* __restrict__ srn, float* __restrict__ sinew,
                         float* __restrict__ frn, float* __restrict__ fin,
                         const float* __restrict__ w_gate, const float* __restrict__ b_gate,
                         float* accum, int step){
  int tid = threadIdx.x;
  int p = blockIdx.x*256 + tid;
  int b = p >> 16, rem = p & 65535;
  int y = rem >> 8, xc = rem & 255;
  const float* xb = x + (size_t)b*6*HW2D;
  float wall = xb[rem];
  float fre = 1.0f - wall;
  float incr=0.0f, inci=0.0f;
  if (y>0)   { incr += fro[p-256]; inci += fio[p-256]; }
  if (y<255) { incr += fro[p+256]; inci += fio[p+256]; }
  if (xc>0)  { incr += fro[p-1];   inci += fio[p-1];   }
  if (xc<255){ incr += fro[p+1];   inci += fio[p+1];   }
  if (step==8){ incr += xb[3*HW2D+rem]; inci += xb[4*HW2D+rem]; }
  float s_r = sro[p], s_i = sio[p], f_r = fro[p], f_i = fio[p];
  size_t padpix = (size_t)b*PP + (y+1)*PW + (xc+1);
  // gate conv (42 ch): hh from packed records
  float a = b_gate[0];
  const short8* hrec = (const short8*)HH + padpix*4;
  #pragma unroll
  for (int q=0;q<4;q++){
    short8 hv = hrec[q];
    #pragma unroll
    for (int j=0;j<8;j++) a += w_gate[q*8+j]*bfu((unsigned short)hv[j]);
  }
  a += w_gate[32]*wall;
  #pragma unroll
  for (int c=1;c<6;c++) a += w_gate[32+c]*xb[c*HW2D+rem];
  a += w_gate[38]*s_r + w_gate[39]*s_i + w_gate[40]*f_r + w_gate[41]*f_i;
  float g = 0.998f + 0.002f*fast_sigmoid(a);
  incr *= g; inci *= g;
  float ca = accum[20], sa = accum[21], dec = accum[22];
  float rr = incr*ca - inci*sa;
  float ri = incr*sa + inci*ca;
  incr = rr*fre; inci = ri*fre;
  float mag = sqrtf(incr*incr + inci*inci + 1e-8f);
  float sc = fminf(2.0f/mag, 1.0f);
  incr *= sc; inci *= sc;
  float pw = (fabsf(incr)+fabsf(inci))*wall;
  float nr = dec*s_r + incr, ni = dec*s_i + inci;
  mag = sqrtf(nr*nr+ni*ni+1e-8f);
  sc = fminf(2.0f/mag, 1.0f);
  nr = nr*sc*fre; ni = ni*sc*fre;
  frn[p]=incr; fin[p]=inci; srn[p]=nr; sinew[p]=ni;
  // pack next-step conv tail: s_r,s_i,f_r,f_i (new)
  ushort4 pk;
  pk.x = f2bfu(nr); pk.y = f2bfu(ni); pk.z = f2bfu(incr); pk.w = f2bfu(inci);
  *(ushort4*)((unsigned short*)TAIL + padpix*16) = pk;
  float d2 = (nr-s_r)*(nr-s_r)+(ni-s_i)*(ni-s_i);
  float nrm = sqrtf(nr*nr+ni*ni);
  #pragma unroll
  for (int off=32; off>0; off>>=1){
    d2  += __shfl_down(d2, off);
    nrm += __shfl_down(nrm, off);
    pw  += __shfl_down(pw, off);
  }
  __shared__ float red[3][4];
  int wid = tid >> 6;
  if ((tid&63)==0){ red[0][wid]=d2; red[1][wid]=nrm; red[2][wid]=pw; }
  __syncthreads();
  if (tid==0){
    atomicAdd(&accum[step-1], red[0][0]+red[0][1]+red[0][2]+red[0][3]);
    atomicAdd(&accum[16],     red[1][0]+red[1][1]+red[1][2]+red[1][3]);
    atomicAdd(&accum[17],     red[2][0]+red[2][1]+red[2][2]+red[2][3]);
  }
}

__global__ void k_tail(const float* __restrict__ x, const float* __restrict__ sr,
                       const float* __restrict__ si, float* accum){
  int tid = threadIdx.x;
  int p = blockIdx.x*256 + tid;
  int b = p >> 16, rem = p & 65535;
  float wall = x[(size_t)b*6*HW2D + rem];
  float vr = sr[p], vi = si[p];
  float sat = (fabsf(vr)>4.0f ? 1.0f:0.0f) + (fabsf(vi)>4.0f ? 1.0f:0.0f);
  float nrm = sqrtf(vr*vr+vi*vi);
  float leak = (nrm>0.5f && wall>0.5f) ? 1.0f : 0.0f;
  #pragma unroll
  for (int off=32; off>0; off>>=1){
    sat  += __shfl_down(sat, off);
    leak += __shfl_down(leak, off);
  }
  __shared__ float red[2][4];
  int wid = tid >> 6;
  if ((tid&63)==0){ red[0][wid]=sat; red[1][wid]=leak; }
  __syncthreads();
  if (tid==0){
    atomicAdd(&accum[18], red[0][0]+red[0][1]+red[0][2]+red[0][3]);
    atomicAdd(&accum[19], red[1][0]+red[1][1]+red[1][2]+red[1][3]);
  }
}

__global__ void k_final(const float* __restrict__ sr, const float* __restrict__ si,
                        const int* __restrict__ target, const float* __restrict__ accum,
                        float* __restrict__ out){
  int t = threadIdx.x;
  if (t < 8){
    int ty = target[2*t], tx = target[2*t+1];
    int p = (t<<16) + (ty<<8) + tx;
    float vr = sr[p], vi = si[p];
    float mag = sqrtf(vr*vr+vi*vi+1e-8f);
    out[t*9] = (0.35f - mag)*12.0f;
    #pragma unroll
    for (int k=0;k<8;k++){
      float th = 6.283185307179586f * (float)k / 8.0f;
      out[t*9+1+k] = (vr*cosf(th)+vi*sinf(th) - 0.35f)*12.0f;
    }
  }
  if (t == 8){
    float d = 0.0f;
    for (int s=0;s<16;s++) d += sqrtf(accum[s]/1048576.0f);
    out[72] = d/16.0f;
    out[73] = accum[16]/8912896.0f;
    out[74] = accum[18]/1048576.0f;
    out[75] = accum[17]/(524288.0f*16.0f);
    out[76] = accum[19]/524288.0f;
  }
}

extern "C" void kernel_launch(void* const* d_in, const int* in_sizes, int n_in,
                              void* d_out, int out_size, void* d_ws, size_t ws_size,
                              hipStream_t stream) {
  const float* x       = (const float*)d_in[0];
  const int*   target  = (const int*)  d_in[1];
  const float* w_in    = (const float*)d_in[2];
  const float* b_in    = (const float*)d_in[3];
  const float* w_up    = (const float*)d_in[4];
  const float* b_up    = (const float*)d_in[5];
  const float* w_gate  = (const float*)d_in[6];
  const float* b_gate  = (const float*)d_in[7];
  const float* angle   = (const float*)d_in[8];
  const float* decay_l = (const float*)d_in[9];
  float* out = (float*)d_out;

  char* ws = (char*)d_ws;
  size_t off = 0;
  bf16* HH0 = (bf16*)(ws+off); off += (size_t)NB*PP*32*sizeof(bf16);
  bf16* HH1 = (bf16*)(ws+off); off += (size_t)NB*PP*32*sizeof(bf16);
  bf16* TAIL= (bf16*)(ws+off); off += (size_t)NB*PP*16*sizeof(bf16);
  float* sr0 = (float*)(ws+off); off += (size_t)NPIX*4;
  float* si0 = (float*)(ws+off); off += (size_t)NPIX*4;
  float* fr0 = (float*)(ws+off); off += (size_t)NPIX*4;
  float* fi0 = (float*)(ws+off); off += (size_t)NPIX*4;
  float* sr1 = (float*)(ws+off); off += (size_t)NPIX*4;
  float* si1 = (float*)(ws+off); off += (size_t)NPIX*4;
  float* fr1 = (float*)(ws+off); off += (size_t)NPIX*4;
  float* fi1 = (float*)(ws+off); off += (size_t)NPIX*4;
  bf16* WB   = (bf16*)(ws+off); off += (size_t)14336*sizeof(bf16);
  float* accum = (float*)(ws+off); off += 32*4;

  k_prep<<<1,32,0,stream>>>(angle, decay_l, accum);
  k_wprep<<<56,256,0,stream>>>(w_up, WB);
  k_border<<<(NB*PP+255)/256,256,0,stream>>>(HH0, HH1, TAIL);
  k_init<<<NPIX/256,256,0,stream>>>(x, w_in, b_in, sr0, si0, fr0, fi0, HH0, TAIL, accum);

  bf16 *hho=HH0, *hhn=HH1;
  float *sro=sr0,*sio=si0,*fro=fr0,*fio=fi0;
  float *srn=sr1,*sinew=si1,*frn=fr1,*fin=fi1;
  for (int t=1;t<=NSTEPS;t++){
    k_conv<<<dim3(256,8),256,0,stream>>>(hho, hhn, TAIL, WB, x, b_up);
    k_step_a<<<NPIX/256,256,0,stream>>>(x, hho, TAIL, sro,sio,fro,fio,
                                        srn,sinew,frn,fin, w_gate, b_gate, accum, t);
    bf16* th_=hho; hho=hhn; hhn=th_;
    float* tp;
    tp=sro; sro=srn; srn=tp;
    tp=sio; sio=sinew; sinew=tp;
    tp=fro; fro=frn; frn=tp;
    tp=fio; fio=fin; fin=tp;
  }
  k_tail<<<NPIX/256,256,0,stream>>>(x, sro, sio, accum);
  k_final<<<1,64,0,stream>>>(sro, sio, target, accum, out);
}

// Round 3
// 1331.702 us; speedup vs baseline: 5.0321x; 1.3428x over previous
//
#include <hip/hip_runtime.h>
#include <hip/hip_bf16.h>

#define HW2D 65536
#define NPIX 524288   // 8 * 65536
#define NB 8
#define PW 258
#define PP 66564      // 258*258
#define NSTEPS 16

typedef __hip_bfloat16 bf16;
typedef __attribute__((ext_vector_type(8))) short short8;
typedef __attribute__((ext_vector_type(4))) float f32x4;

__device__ __forceinline__ float bf2f(bf16 v){ return __bfloat162float(v); }
__device__ __forceinline__ bf16 f2bf(float v){ return __float2bfloat16(v); }
__device__ __forceinline__ float bfu(unsigned short u){
  unsigned int t = ((unsigned int)u) << 16; return __uint_as_float(t);
}
__device__ __forceinline__ unsigned short f2bfu(float v){
  bf16 h = __float2bfloat16(v); return *(unsigned short*)&h;
}

__device__ __forceinline__ float fast_tanh(float z){
  float az = fabsf(z);
  float e = __expf(2.0f*az);
  float t = 1.0f - 2.0f/(e+1.0f);
  return copysignf(t, z);
}
__device__ __forceinline__ float fast_sigmoid(float z){
  return 1.0f/(1.0f + __expf(-z));
}

// accum: [0..15] per-step diff2, [16] norm, [17] pw, [18] sat, [19] leak,
// [20] cos_a, [21] sin_a, [22] decay
__global__ void k_prep(const float* angle, const float* decay_logit, float* accum){
  int t = threadIdx.x;
  if (t < 20) accum[t] = 0.0f;
  if (t == 0){
    float ang = tanhf(angle[0])*0.02f;
    accum[20] = cosf(ang);
    accum[21] = sinf(ang);
    accum[22] = 0.95f + 0.05f/(1.0f+expf(-decay_logit[0]));
  }
}

// WB[((n*14+s)*64+lane)*8+j] : per-lane B fragments, bf16 (see round-2 comment)
__global__ void k_wprep(const float* __restrict__ w_up, bf16* __restrict__ WB){
  int idx = blockIdx.x*256 + threadIdx.x;
  if (idx >= 14336) return;
  int j = idx & 7;
  int lane = (idx >> 3) & 63;
  int s = (idx >> 9) % 14;
  int n = idx / 7168;
  int oc = n*16 + (lane & 15);
  int g = lane >> 4;
  float w = 0.0f;
  if (s < 9){
    int ch = g*8 + j;
    int dy = s/3, dx = s%3;
    w = w_up[((oc*42 + ch)*3 + dy)*3 + dx];
  } else {
    int s2 = s - 9;
    int tap = 2*s2 + (g>>1);
    int t = (g&1)*8 + j;
    if (tap <= 8 && t < 10){
      int src = (t < 4) ? (38 + t) : (32 + (t-4));
      int dy = tap/3, dx = tap%3;
      w = w_up[((oc*42 + src)*3 + dy)*3 + dx];
    }
  }
  WB[idx] = f2bf(w);
}

__global__ void k_border(bf16* HH0, bf16* HH1, bf16* TAIL0, bf16* TAIL1){
  int i = blockIdx.x*256 + threadIdx.x;
  if (i >= NB*PP) return;
  int pp_ = i % PP;
  int r = pp_ / PW, c = pp_ % PW;
  if (r != 0 && r != 257 && c != 0 && c != 257) return;
  short8 z = (short8){0,0,0,0,0,0,0,0};
  short8* h0 = (short8*)HH0 + (size_t)i*4;
  short8* h1 = (short8*)HH1 + (size_t)i*4;
  short8* t0 = (short8*)TAIL0 + (size_t)i*2;
  short8* t1 = (short8*)TAIL1 + (size_t)i*2;
  h0[0]=z; h0[1]=z; h0[2]=z; h0[3]=z;
  h1[0]=z; h1[1]=z; h1[2]=z; h1[3]=z;
  t0[0]=z; t0[1]=z; t1[0]=z; t1[1]=z;
}

__global__ void k_init(const float* __restrict__ x, const float* __restrict__ w_in,
                       const float* __restrict__ b_in,
                       const float* __restrict__ w_gate, const float* __restrict__ b_gate,
                       float4* __restrict__ SF0, float2* __restrict__ WG,
                       bf16* __restrict__ HH0, bf16* __restrict__ TAIL0,
                       bf16* __restrict__ TAIL1, float* accum){
  int tid = threadIdx.x;
  int p = blockIdx.x*256 + tid;
  int b = p >> 16, rem = p & 65535;
  int y = rem >> 8, xc = rem & 255;
  const float* xb = x + (size_t)b*6*HW2D;
  float wall = xb[rem];
  float fre = 1.0f - wall;
  float s_r = xb[HW2D + rem]*fre;
  float s_i = xb[2*HW2D + rem]*fre;
  SF0[p] = (float4){s_r, s_i, s_r, s_i};
  float src10[10];
  src10[0]=wall;
  #pragma unroll
  for (int c=1;c<6;c++) src10[c]=xb[c*HW2D+rem];
  src10[6]=s_r; src10[7]=s_i; src10[8]=s_r; src10[9]=s_i;
  float gx = b_gate[0];
  #pragma unroll
  for (int c=0;c<6;c++) gx += w_gate[32+c]*src10[c];
  WG[p] = (float2){wall, gx};
  size_t padpix = (size_t)b*PP + (y+1)*PW + (xc+1);
  unsigned short hv[32];
  #pragma unroll
  for (int c=0;c<32;c++){
    float a = b_in[c];
    #pragma unroll
    for (int k=0;k<10;k++) a += w_in[c*10+k]*src10[k];
    hv[c] = f2bfu(fast_tanh(a)*fre);
  }
  short8* hrec = (short8*)HH0 + padpix*4;
  #pragma unroll
  for (int q=0;q<4;q++){
    short8 v;
    #pragma unroll
    for (int j=0;j<8;j++) v[j] = (short)hv[q*8+j];
    hrec[q] = v;
  }
  unsigned short tv[16];
  tv[0]=f2bfu(s_r); tv[1]=f2bfu(s_i); tv[2]=f2bfu(s_r); tv[3]=f2bfu(s_i);
  #pragma unroll
  for (int c=0;c<6;c++) tv[4+c] = f2bfu(src10[c]);
  #pragma unroll
  for (int c=10;c<16;c++) tv[c] = 0;
  #pragma unroll
  for (int q=0;q<2;q++){
    short8 v;
    #pragma unroll
    for (int j=0;j<8;j++) v[j] = (short)tv[q*8+j];
    ((short8*)TAIL0)[padpix*2+q] = v;
    ((short8*)TAIL1)[padpix*2+q] = v;
  }
  float v = sqrtf(s_r*s_r + s_i*s_i);
  #pragma unroll
  for (int off=32; off>0; off>>=1) v += __shfl_down(v, off);
  __shared__ float red[4];
  int wid = tid >> 6;
  if ((tid&63)==0) red[wid] = v;
  __syncthreads();
  if (tid==0) atomicAdd(&accum[16], red[0]+red[1]+red[2]+red[3]);
}

// Fused per-step kernel: phase A = MFMA implicit-GEMM 3x3 conv (hh update),
// phase B = stencil + gate + rotate/clamp state update + stats.
// One block per (row,batch); b = bid&7 so each XCD streams one batch's band.
__global__ __launch_bounds__(256) void k_step(
    const bf16* __restrict__ HHo, bf16* __restrict__ HHn,
    const bf16* __restrict__ TAILo, bf16* __restrict__ TAILn,
    const float4* __restrict__ SFo, float4* __restrict__ SFn,
    const float2* __restrict__ WG, const bf16* __restrict__ WB,
    const float* __restrict__ b_up, const float* __restrict__ x,
    const float* __restrict__ w_gate, float* accum, int step){
  int bid = blockIdx.x;
  int b = bid & 7, y = bid >> 3;
  int tid = threadIdx.x;
  int wv = tid >> 6, lane = tid & 63;
  int r_ = lane & 15, g = lane >> 4;
  int bbase = b*PP;
  int rowbase = (y+1)*PW + 1;

  // ---- phase A: conv ----
  int pix[4];
  #pragma unroll
  for (int mt=0;mt<4;mt++) pix[mt] = bbase + rowbase + wv*64 + mt*16 + r_;
  f32x4 acc[4][2];
  #pragma unroll
  for (int mt=0;mt<4;mt++){
    acc[mt][0] = (f32x4){0.f,0.f,0.f,0.f};
    acc[mt][1] = (f32x4){0.f,0.f,0.f,0.f};
  }
  const short8* HH8 = (const short8*)HHo;
  const short8* T8  = (const short8*)TAILo;
  const short8* wb  = (const short8*)WB;

  #pragma unroll
  for (int s=0;s<9;s++){
    const int off = (s/3 - 1)*PW + (s%3 - 1);
    short8 b0 = wb[s*64 + lane];
    short8 b1 = wb[(14+s)*64 + lane];
    #pragma unroll
    for (int mt=0;mt<4;mt++){
      short8 a = HH8[(size_t)(pix[mt]+off)*4 + g];
      acc[mt][0] = __builtin_amdgcn_mfma_f32_16x16x32_bf16(a, b0, acc[mt][0], 0,0,0);
      acc[mt][1] = __builtin_amdgcn_mfma_f32_16x16x32_bf16(a, b1, acc[mt][1], 0,0,0);
    }
  }
  #pragma unroll
  for (int s2=0;s2<5;s2++){
    int s = 9+s2;
    short8 b0 = wb[s*64 + lane];
    short8 b1 = wb[(14+s)*64 + lane];
    const int tA = 2*s2, tB = 2*s2+1;
    const int offA = (tA/3 - 1)*PW + (tA%3 - 1);
    const int offB = (tB <= 8) ? ((tB/3 - 1)*PW + (tB%3 - 1)) : 0;
    bool hiB = (g >= 2);
    #pragma unroll
    for (int mt=0;mt<4;mt++){
      int tp;
      if (tB <= 8) tp = pix[mt] + (hiB ? offB : offA);
      else         tp = hiB ? bbase : (pix[mt] + offA);
      short8 a = T8[(size_t)tp*2 + (g&1)];
      acc[mt][0] = __builtin_amdgcn_mfma_f32_16x16x32_bf16(a, b0, acc[mt][0], 0,0,0);
      acc[mt][1] = __builtin_amdgcn_mfma_f32_16x16x32_bf16(a, b1, acc[mt][1], 0,0,0);
    }
  }
  const float2* wgrow = WG + (size_t)b*HW2D + y*256;
  float bias0 = b_up[r_], bias1 = b_up[16 + r_];
  #pragma unroll
  for (int mt=0;mt<4;mt++){
    #pragma unroll
    for (int i=0;i<4;i++){
      int px = wv*64 + mt*16 + g*4 + i;
      float fre = 1.0f - wgrow[px].x;
      size_t hof = (size_t)(bbase + rowbase + px)*32;
      float h0 = bf2f(HHo[hof + r_]);
      float h1 = bf2f(HHo[hof + 16 + r_]);
      HHn[hof + r_]      = f2bf(fast_tanh(0.8f*h0 + acc[mt][0][i] + bias0)*fre);
      HHn[hof + 16 + r_] = f2bf(fast_tanh(0.8f*h1 + acc[mt][1][i] + bias1)*fre);
    }
  }

  // ---- phase B: state update ----
  int p = b*HW2D + (y<<8) + tid;
  float4 c = SFo[p];
  float s_r = c.x, s_i = c.y, f_r = c.z, f_i = c.w;
  float incr = 0.0f, inci = 0.0f;
  if (y>0)   { float4 n = SFo[p-256]; incr += n.z; inci += n.w; }
  if (y<255) { float4 n = SFo[p+256]; incr += n.z; inci += n.w; }
  if (tid>0)  { float4 n = SFo[p-1];  incr += n.z; inci += n.w; }
  if (tid<255){ float4 n = SFo[p+1];  incr += n.z; inci += n.w; }
  if (step==8){
    const float* xb = x + (size_t)b*6*HW2D;
    int rem = (y<<8)+tid;
    incr += xb[3*HW2D+rem]; inci += xb[4*HW2D+rem];
  }
  float2 wg = wgrow[tid];
  float wall = wg.x;
  float fre = 1.0f - wall;
  size_t padpix = (size_t)bbase + rowbase + tid;
  float a = wg.y;
  const short8* hrec = (const short8*)HHo + padpix*4;
  #pragma unroll
  for (int q=0;q<4;q++){
    short8 hv = hrec[q];
    #pragma unroll
    for (int j=0;j<8;j++) a += w_gate[q*8+j]*bfu((unsigned short)hv[j]);
  }
  a += w_gate[38]*s_r + w_gate[39]*s_i + w_gate[40]*f_r + w_gate[41]*f_i;
  float gg = 0.998f + 0.002f*fast_sigmoid(a);
  incr *= gg; inci *= gg;
  float ca = accum[20], sa = accum[21], dec = accum[22];
  float rr = incr*ca - inci*sa;
  float ri = incr*sa + inci*ca;
  incr = rr*fre; inci = ri*fre;
  float mag = sqrtf(incr*incr + inci*inci + 1e-8f);
  float sc = fminf(2.0f/mag, 1.0f);
  incr *= sc; inci *= sc;
  float pw = (fabsf(incr)+fabsf(inci))*wall;
  float nr = dec*s_r + incr, ni = dec*s_i + inci;
  mag = sqrtf(nr*nr+ni*ni+1e-8f);
  sc = fminf(2.0f/mag, 1.0f);
  nr = nr*sc*fre; ni = ni*sc*fre;
  SFn[p] = (float4){nr, ni, incr, inci};
  ushort4 pk;
  pk.x = f2bfu(nr); pk.y = f2bfu(ni); pk.z = f2bfu(incr); pk.w = f2bfu(inci);
  *(ushort4*)((unsigned short*)TAILn + padpix*16) = pk;
  float d2 = (nr-s_r)*(nr-s_r)+(ni-s_i)*(ni-s_i);
  float nrm = sqrtf(nr*nr+ni*ni);
  #pragma unroll
  for (int off=32; off>0; off>>=1){
    d2  += __shfl_down(d2, off);
    nrm += __shfl_down(nrm, off);
    pw  += __shfl_down(pw, off);
  }
  __shared__ float red[3][4];
  int wid = tid >> 6;
  if ((tid&63)==0){ red[0][wid]=d2; red[1][wid]=nrm; red[2][wid]=pw; }
  __syncthreads();
  if (tid==0){
    atomicAdd(&accum[step-1], red[0][0]+red[0][1]+red[0][2]+red[0][3]);
    atomicAdd(&accum[16],     red[1][0]+red[1][1]+red[1][2]+red[1][3]);
    atomicAdd(&accum[17],     red[2][0]+red[2][1]+red[2][2]+red[2][3]);
  }
}

__global__ void k_tail(const float2* __restrict__ WG, const float4* __restrict__ SF,
                       float* accum){
  int tid = threadIdx.x;
  int p = blockIdx.x*256 + tid;
  float wall = WG[p].x;
  float4 c = SF[p];
  float vr = c.x, vi = c.y;
  float sat = (fabsf(vr)>4.0f ? 1.0f:0.0f) + (fabsf(vi)>4.0f ? 1.0f:0.0f);
  float nrm = sqrtf(vr*vr+vi*vi);
  float leak = (nrm>0.5f && wall>0.5f) ? 1.0f : 0.0f;
  #pragma unroll
  for (int off=32; off>0; off>>=1){
    sat  += __shfl_down(sat, off);
    leak += __shfl_down(leak, off);
  }
  __shared__ float red[2][4];
  int wid = tid >> 6;
  if ((tid&63)==0){ red[0][wid]=sat; red[1][wid]=leak; }
  __syncthreads();
  if (tid==0){
    atomicAdd(&accum[18], red[0][0]+red[0][1]+red[0][2]+red[0][3]);
    atomicAdd(&accum[19], red[1][0]+red[1][1]+red[1][2]+red[1][3]);
  }
}

__global__ void k_final(const float4* __restrict__ SF, const int* __restrict__ target,
                        const float* __restrict__ accum, float* __restrict__ out){
  int t = threadIdx.x;
  if (t < 8){
    int ty = target[2*t], tx = target[2*t+1];
    int p = (t<<16) + (ty<<8) + tx;
    float4 c = SF[p];
    float vr = c.x, vi = c.y;
    float mag = sqrtf(vr*vr+vi*vi+1e-8f);
    out[t*9] = (0.35f - mag)*12.0f;
    #pragma unroll
    for (int k=0;k<8;k++){
      float th = 6.283185307179586f * (float)k / 8.0f;
      out[t*9+1+k] = (vr*cosf(th)+vi*sinf(th) - 0.35f)*12.0f;
    }
  }
  if (t == 8){
    float d = 0.0f;
    for (int s=0;s<16;s++) d += sqrtf(accum[s]/1048576.0f);
    out[72] = d/16.0f;
    out[73] = accum[16]/8912896.0f;
    out[74] = accum[18]/1048576.0f;
    out[75] = accum[17]/(524288.0f*16.0f);
    out[76] = accum[19]/524288.0f;
  }
}

extern "C" void kernel_launch(void* const* d_in, const int* in_sizes, int n_in,
                              void* d_out, int out_size, void* d_ws, size_t ws_size,
                              hipStream_t stream) {
  const float* x       = (const float*)d_in[0];
  const int*   target  = (const int*)  d_in[1];
  const float* w_in    = (const float*)d_in[2];
  const float* b_in    = (const float*)d_in[3];
  const float* w_up    = (const float*)d_in[4];
  const float* b_up    = (const float*)d_in[5];
  const float* w_gate  = (const float*)d_in[6];
  const float* b_gate  = (const float*)d_in[7];
  const float* angle   = (const float*)d_in[8];
  const float* decay_l = (const float*)d_in[9];
  float* out = (float*)d_out;

  char* ws = (char*)d_ws;
  size_t off = 0;
  bf16* HH0 = (bf16*)(ws+off); off += (size_t)NB*PP*32*sizeof(bf16);
  bf16* HH1 = (bf16*)(ws+off); off += (size_t)NB*PP*32*sizeof(bf16);
  bf16* TAIL0=(bf16*)(ws+off); off += (size_t)NB*PP*16*sizeof(bf16);
  bf16* TAIL1=(bf16*)(ws+off); off += (size_t)NB*PP*16*sizeof(bf16);
  float4* SF0 = (float4*)(ws+off); off += (size_t)NPIX*16;
  float4* SF1 = (float4*)(ws+off); off += (size_t)NPIX*16;
  float2* WG  = (float2*)(ws+off); off += (size_t)NPIX*8;
  bf16* WB   = (bf16*)(ws+off); off += (size_t)14336*sizeof(bf16);
  float* accum = (float*)(ws+off); off += 32*4;

  k_prep<<<1,32,0,stream>>>(angle, decay_l, accum);
  k_wprep<<<56,256,0,stream>>>(w_up, WB);
  k_border<<<(NB*PP+255)/256,256,0,stream>>>(HH0, HH1, TAIL0, TAIL1);
  k_init<<<NPIX/256,256,0,stream>>>(x, w_in, b_in, w_gate, b_gate,
                                    SF0, WG, HH0, TAIL0, TAIL1, accum);

  bf16 *hho=HH0, *hhn=HH1, *tlo=TAIL0, *tln=TAIL1;
  float4 *sfo=SF0, *sfn=SF1;
  for (int t=1;t<=NSTEPS;t++){
    k_step<<<2048,256,0,stream>>>(hho, hhn, tlo, tln, sfo, sfn, WG, WB,
                                  b_up, x, w_gate, accum, t);
    bf16* th_=hho; hho=hhn; hhn=th_;
    th_=tlo; tlo=tln; tln=th_;
    float4* tf=sfo; sfo=sfn; sfn=tf;
  }
  k_tail<<<NPIX/256,256,0,stream>>>(WG, sfo, accum);
  k_final<<<1,64,0,stream>>>(sfo, target, accum, out);
}

// Round 4
// 1252.780 us; speedup vs baseline: 5.3491x; 1.0630x over previous
//
#include <hip/hip_runtime.h>
#include <hip/hip_bf16.h>

#define HW2D 65536
#define NPIX 524288   // 8 * 65536
#define NB 8
#define PW 258
#define PP 66564      // 258*258
#define NSTEPS 16
#define OFF9(s) (((s)/3 - 1)*PW + ((s)%3 - 1))

typedef __hip_bfloat16 bf16;
typedef unsigned long long u64;
typedef __attribute__((ext_vector_type(8))) short short8;
typedef __attribute__((ext_vector_type(4))) float f32x4;

__device__ __forceinline__ float bf2f(bf16 v){ return __bfloat162float(v); }
__device__ __forceinline__ unsigned short f2bfu(float v){
  bf16 h = __float2bfloat16(v); return *(unsigned short*)&h;
}
__device__ __forceinline__ float fast_tanh(float z){
  float az = fabsf(z);
  float e = __expf(2.0f*az);
  float t = 1.0f - 2.0f/(e+1.0f);
  return copysignf(t, z);
}
__device__ __forceinline__ float fast_sigmoid(float z){
  return 1.0f/(1.0f + __expf(-z));
}
__device__ __forceinline__ unsigned char f2fp8(float v){
  return (unsigned char)(__builtin_amdgcn_cvt_pk_fp8_f32(v, 0.f, 0, false) & 0xFF);
}

// accum: [0..15] per-step diff2, [16] norm, [17] pw, [18] sat, [19] leak,
// [20] cos_a, [21] sin_a, [22] decay
__global__ void k_prep(const float* angle, const float* decay_logit, float* accum){
  int t = threadIdx.x;
  if (t < 20) accum[t] = 0.0f;
  if (t == 0){
    float ang = tanhf(angle[0])*0.02f;
    accum[20] = cosf(ang);
    accum[21] = sinf(ang);
    accum[22] = 0.95f + 0.05f/(1.0f+expf(-decay_logit[0]));
  }
}

// WB8: fp8 B-fragments. slots 0-8: tile0 (oc 0-15) taps 0-8; 9-17: tile1;
// 18: gate column (center tap, hh channels). lane: r_=oc, g*8+j = in-ch.
// Center tap (s=4) has +0.8 on the oc==ch diagonal (folds 0.8*hh_old).
// WB16: bf16 B-fragments for tail. slots 0-4: tile0 pairs; 5-9: tile1;
// 10: gate column (center-tap tail channels).
__global__ void k_wprep(const float* __restrict__ w_up, const float* __restrict__ w_gate,
                        u64* __restrict__ WB8, short8* __restrict__ WB16){
  int t = threadIdx.x;
  int lane = t & 63;
  int r_ = lane & 15, g = lane >> 4;
  for (int slot = t>>6; slot < 19; slot += 4){
    u64 v = 0;
    #pragma unroll
    for (int j=0;j<8;j++){
      float w = 0.f;
      int ch = g*8+j;
      if (slot < 18){
        int tile = slot/9, s = slot%9;
        int oc = tile*16 + r_;
        int dy=s/3, dx=s%3;
        w = w_up[((oc*42+ch)*3+dy)*3+dx];
        if (s==4 && oc==ch) w += 0.8f;
      } else {
        if (r_==0) w = w_gate[ch];
      }
      v |= ((u64)f2fp8(w)) << (8*j);
    }
    WB8[slot*64+lane] = v;
  }
  for (int slot = t>>6; slot < 11; slot += 4){
    short8 v;
    #pragma unroll
    for (int j=0;j<8;j++){
      float w = 0.f;
      int tt = (g&1)*8 + j;
      int tapsel = g>>1;
      if (slot < 10){
        int tile = slot/5, s2 = slot%5;
        int tap = 2*s2 + tapsel;
        int oc = tile*16 + r_;
        if (tap <= 8 && tt < 10){
          int src = (tt<4) ? (38+tt) : (32+(tt-4));
          int dy=tap/3, dx=tap%3;
          w = w_up[((oc*42+src)*3+dy)*3+dx];
        }
      } else {
        if (r_==0 && tapsel==0 && tt<10){
          int src = (tt<4) ? (38+tt) : (32+(tt-4));
          w = w_gate[src];
        }
      }
      v[j] = (short)f2bfu(w);
    }
    WB16[slot*64+lane] = v;
  }
}

__global__ void k_border(unsigned char* HH0, unsigned char* HH1, bf16* TAIL0, bf16* TAIL1){
  int i = blockIdx.x*256 + threadIdx.x;
  if (i >= NB*PP) return;
  int pp_ = i % PP;
  int r = pp_ / PW, c = pp_ % PW;
  if (r != 0 && r != 257 && c != 0 && c != 257) return;
  short8 z = (short8){0,0,0,0,0,0,0,0};
  ((short8*)HH0)[(size_t)i*2]   = z; ((short8*)HH0)[(size_t)i*2+1] = z;
  ((short8*)HH1)[(size_t)i*2]   = z; ((short8*)HH1)[(size_t)i*2+1] = z;
  ((short8*)TAIL0)[(size_t)i*2] = z; ((short8*)TAIL0)[(size_t)i*2+1] = z;
  ((short8*)TAIL1)[(size_t)i*2] = z; ((short8*)TAIL1)[(size_t)i*2+1] = z;
}

__global__ void k_init(const float* __restrict__ x, const float* __restrict__ w_in,
                       const float* __restrict__ b_in,
                       float2* __restrict__ S0, float2* __restrict__ F0,
                       float* __restrict__ WALL,
                       unsigned char* __restrict__ HH0, bf16* __restrict__ TAIL0,
                       bf16* __restrict__ TAIL1, float* accum){
  int tid = threadIdx.x;
  int p = blockIdx.x*256 + tid;
  int b = p >> 16, rem = p & 65535;
  int y = rem >> 8, xc = rem & 255;
  const float* xb = x + (size_t)b*6*HW2D;
  float wall = xb[rem];
  float fre = 1.0f - wall;
  float s_r = xb[HW2D + rem]*fre;
  float s_i = xb[2*HW2D + rem]*fre;
  S0[p] = (float2){s_r, s_i};
  F0[p] = (float2){s_r, s_i};
  WALL[p] = wall;
  float src10[10];
  src10[0]=wall;
  #pragma unroll
  for (int c=1;c<6;c++) src10[c]=xb[c*HW2D+rem];
  src10[6]=s_r; src10[7]=s_i; src10[8]=s_r; src10[9]=s_i;
  size_t padpix = (size_t)b*PP + (y+1)*PW + (xc+1);
  float hv[32];
  #pragma unroll
  for (int c=0;c<32;c++){
    float a = b_in[c];
    #pragma unroll
    for (int k=0;k<10;k++) a += w_in[c*10+k]*src10[k];
    hv[c] = fast_tanh(a)*fre;
  }
  unsigned int words[8];
  #pragma unroll
  for (int w=0;w<8;w++){
    int lo = __builtin_amdgcn_cvt_pk_fp8_f32(hv[4*w], hv[4*w+1], 0, false);
    words[w] = (unsigned int)__builtin_amdgcn_cvt_pk_fp8_f32(hv[4*w+2], hv[4*w+3], lo, true);
  }
  uint4* hrec = (uint4*)(HH0 + padpix*32);
  hrec[0] = (uint4){words[0],words[1],words[2],words[3]};
  hrec[1] = (uint4){words[4],words[5],words[6],words[7]};
  unsigned short tv[16];
  tv[0]=f2bfu(s_r); tv[1]=f2bfu(s_i); tv[2]=f2bfu(s_r); tv[3]=f2bfu(s_i);
  #pragma unroll
  for (int c=0;c<6;c++) tv[4+c] = f2bfu(src10[c]);
  #pragma unroll
  for (int c=10;c<16;c++) tv[c] = 0;
  #pragma unroll
  for (int q=0;q<2;q++){
    short8 v;
    #pragma unroll
    for (int j=0;j<8;j++) v[j] = (short)tv[q*8+j];
    ((short8*)TAIL0)[padpix*2+q] = v;
    ((short8*)TAIL1)[padpix*2+q] = v;
  }
  float v = sqrtf(s_r*s_r + s_i*s_i);
  #pragma unroll
  for (int off=32; off>0; off>>=1) v += __shfl_down(v, off);
  __shared__ float red[4];
  int wid = tid >> 6;
  if ((tid&63)==0) red[wid] = v;
  __syncthreads();
  if (tid==0) atomicAdd(&accum[16], red[0]+red[1]+red[2]+red[3]);
}

// Fused step: phase A = fp8/bf16 MFMA conv (+gate column), phase B = state update.
__global__ __launch_bounds__(256) void k_step(
    const unsigned char* __restrict__ HHo, unsigned char* __restrict__ HHn,
    const bf16* __restrict__ TAILo, bf16* __restrict__ TAILn,
    const float2* __restrict__ So, float2* __restrict__ Sn,
    const float2* __restrict__ Fo, float2* __restrict__ Fn,
    const float* __restrict__ WALL,
    const u64* __restrict__ WB8, const short8* __restrict__ WB16,
    const float* __restrict__ b_up, const float* __restrict__ x,
    const float* __restrict__ b_gate, float* accum, int step){
  int bid = blockIdx.x;
  int b = bid & 7, y = bid >> 3;
  int tid = threadIdx.x;
  int wv = tid >> 6, lane = tid & 63;
  int r_ = lane & 15, g = lane >> 4;
  int bbase = b*PP;
  int rowbase = (y+1)*PW + 1;
  __shared__ float lgate[256];
  __shared__ float red[3][4];

  // ---- phase A ----
  int pix[4];
  #pragma unroll
  for (int mt=0;mt<4;mt++) pix[mt] = bbase + rowbase + wv*64 + mt*16 + r_;
  f32x4 acc[4][2], accg[4];
  #pragma unroll
  for (int mt=0;mt<4;mt++){
    acc[mt][0] = (f32x4){0.f,0.f,0.f,0.f};
    acc[mt][1] = (f32x4){0.f,0.f,0.f,0.f};
    accg[mt]   = (f32x4){0.f,0.f,0.f,0.f};
  }
  const u64* HH8 = (const u64*)HHo;
  const short8* T8 = (const short8*)TAILo;

  // seg1: 9 taps x 32 hh channels, fp8, 1-tap prefetch
  u64 aF[4], aN[4];
  #pragma unroll
  for (int mt=0;mt<4;mt++) aF[mt] = HH8[(size_t)(pix[mt]+OFF9(0))*4 + g];
  #pragma unroll
  for (int s=0;s<9;s++){
    if (s<8){
      #pragma unroll
      for (int mt=0;mt<4;mt++) aN[mt] = HH8[(size_t)(pix[mt]+OFF9(s+1))*4 + g];
    }
    u64 b0 = WB8[s*64+lane], b1 = WB8[(9+s)*64+lane];
    #pragma unroll
    for (int mt=0;mt<4;mt++){
      acc[mt][0] = __builtin_amdgcn_mfma_f32_16x16x32_fp8_fp8((long)aF[mt], (long)b0, acc[mt][0], 0,0,0);
      acc[mt][1] = __builtin_amdgcn_mfma_f32_16x16x32_fp8_fp8((long)aF[mt], (long)b1, acc[mt][1], 0,0,0);
    }
    if (s==4){
      u64 bg = WB8[18*64+lane];
      #pragma unroll
      for (int mt=0;mt<4;mt++)
        accg[mt] = __builtin_amdgcn_mfma_f32_16x16x32_fp8_fp8((long)aF[mt], (long)bg, accg[mt], 0,0,0);
    }
    if (s<8){
      #pragma unroll
      for (int mt=0;mt<4;mt++) aF[mt] = aN[mt];
    }
  }
  // seg2: 5 pair-steps x 16 tail channels, bf16, 1-step prefetch
  short8 tF[4], tN[4];
  {
    const int offA0 = OFF9(0), offB0 = OFF9(1);
    bool hiB = (g >= 2);
    #pragma unroll
    for (int mt=0;mt<4;mt++)
      tF[mt] = T8[(size_t)(pix[mt] + (hiB ? offB0 : offA0))*2 + (g&1)];
  }
  #pragma unroll
  for (int s2=0;s2<5;s2++){
    if (s2<4){
      const int tA = 2*(s2+1), tB = 2*(s2+1)+1;
      const int offA = OFF9(tA);
      const int offB = (tB <= 8) ? OFF9(tB) : 0;
      bool hiB = (g >= 2);
      #pragma unroll
      for (int mt=0;mt<4;mt++){
        int tp;
        if (tB <= 8) tp = pix[mt] + (hiB ? offB : offA);
        else         tp = hiB ? bbase : (pix[mt] + offA);
        tN[mt] = T8[(size_t)tp*2 + (g&1)];
      }
    }
    short8 b0 = WB16[s2*64+lane], b1 = WB16[(5+s2)*64+lane];
    #pragma unroll
    for (int mt=0;mt<4;mt++){
      acc[mt][0] = __builtin_amdgcn_mfma_f32_16x16x32_bf16(tF[mt], b0, acc[mt][0], 0,0,0);
      acc[mt][1] = __builtin_amdgcn_mfma_f32_16x16x32_bf16(tF[mt], b1, acc[mt][1], 0,0,0);
    }
    if (s2==2){
      short8 bgt = WB16[10*64+lane];
      #pragma unroll
      for (int mt=0;mt<4;mt++)
        accg[mt] = __builtin_amdgcn_mfma_f32_16x16x32_bf16(tF[mt], bgt, accg[mt], 0,0,0);
    }
    if (s2<4){
      #pragma unroll
      for (int mt=0;mt<4;mt++) tF[mt] = tN[mt];
    }
  }
  // gate redistribution (col 0 lanes hold the gate pre-activation)
  if (r_ == 0){
    #pragma unroll
    for (int mt=0;mt<4;mt++){
      #pragma unroll
      for (int i=0;i<4;i++) lgate[wv*64 + mt*16 + g*4 + i] = accg[mt][i];
    }
  }

  // issue phase-B global loads (latency hidden under epilogue VALU)
  int p = b*HW2D + (y<<8) + tid;
  float2 sc = So[p];
  float2 fup = (y>0)    ? Fo[p-256] : (float2){0.f,0.f};
  float2 fdn = (y<255)  ? Fo[p+256] : (float2){0.f,0.f};
  float2 flt = (tid>0)  ? Fo[p-1]   : (float2){0.f,0.f};
  float2 frt = (tid<255)? Fo[p+1]   : (float2){0.f,0.f};
  float dlr = 0.f, dli = 0.f;
  if (step==8){
    const float* xb = x + (size_t)b*6*HW2D;
    int rem = (y<<8)+tid;
    dlr = xb[3*HW2D+rem]; dli = xb[4*HW2D+rem];
  }
  float wallB = WALL[p];

  // epilogue: hh_new = tanh(acc + bias) * free   (0.8*hh_old folded into weights)
  const float* wallrow = WALL + (size_t)b*HW2D + y*256;
  float bias0 = b_up[r_], bias1 = b_up[16 + r_];
  #pragma unroll
  for (int mt=0;mt<4;mt++){
    #pragma unroll
    for (int i=0;i<4;i++){
      int px = wv*64 + mt*16 + g*4 + i;
      float fre = 1.0f - wallrow[px];
      size_t hof = (size_t)(bbase + rowbase + px)*32;
      HHn[hof + r_]      = f2fp8(fast_tanh(acc[mt][0][i] + bias0)*fre);
      HHn[hof + 16 + r_] = f2fp8(fast_tanh(acc[mt][1][i] + bias1)*fre);
    }
  }
  __syncthreads();

  // ---- phase B ----
  float s_r = sc.x, s_i = sc.y;
  float incr = fup.x + fdn.x + flt.x + frt.x + dlr;
  float inci = fup.y + fdn.y + flt.y + frt.y + dli;
  float fre = 1.0f - wallB;
  float a = lgate[tid] + b_gate[0];
  float gg = 0.998f + 0.002f*fast_sigmoid(a);
  incr *= gg; inci *= gg;
  float ca = accum[20], sa = accum[21], dec = accum[22];
  float rr = incr*ca - inci*sa;
  float ri = incr*sa + inci*ca;
  incr = rr*fre; inci = ri*fre;
  float mag = sqrtf(incr*incr + inci*inci + 1e-8f);
  float sc2 = fminf(2.0f/mag, 1.0f);
  incr *= sc2; inci *= sc2;
  float pw = (fabsf(incr)+fabsf(inci))*wallB;
  float nr = dec*s_r + incr, ni = dec*s_i + inci;
  mag = sqrtf(nr*nr+ni*ni+1e-8f);
  sc2 = fminf(2.0f/mag, 1.0f);
  nr = nr*sc2*fre; ni = ni*sc2*fre;
  Sn[p] = (float2){nr, ni};
  Fn[p] = (float2){incr, inci};
  size_t padpix = (size_t)bbase + rowbase + tid;
  ushort4 pk;
  pk.x = f2bfu(nr); pk.y = f2bfu(ni); pk.z = f2bfu(incr); pk.w = f2bfu(inci);
  *(ushort4*)((unsigned short*)TAILn + padpix*16) = pk;
  float d2 = (nr-s_r)*(nr-s_r)+(ni-s_i)*(ni-s_i);
  float nrm = sqrtf(nr*nr+ni*ni);
  #pragma unroll
  for (int off=32; off>0; off>>=1){
    d2  += __shfl_down(d2, off);
    nrm += __shfl_down(nrm, off);
    pw  += __shfl_down(pw, off);
  }
  int wid = tid >> 6;
  if ((tid&63)==0){ red[0][wid]=d2; red[1][wid]=nrm; red[2][wid]=pw; }
  __syncthreads();
  if (tid==0){
    atomicAdd(&accum[step-1], red[0][0]+red[0][1]+red[0][2]+red[0][3]);
    atomicAdd(&accum[16],     red[1][0]+red[1][1]+red[1][2]+red[1][3]);
    atomicAdd(&accum[17],     red[2][0]+red[2][1]+red[2][2]+red[2][3]);
  }
}

__global__ void k_tail(const float* __restrict__ WALL, const float2* __restrict__ S,
                       float* accum){
  int tid = threadIdx.x;
  int p = blockIdx.x*256 + tid;
  float wall = WALL[p];
  float2 c = S[p];
  float vr = c.x, vi = c.y;
  float sat = (fabsf(vr)>4.0f ? 1.0f:0.0f) + (fabsf(vi)>4.0f ? 1.0f:0.0f);
  float nrm = sqrtf(vr*vr+vi*vi);
  float leak = (nrm>0.5f && wall>0.5f) ? 1.0f : 0.0f;
  #pragma unroll
  for (int off=32; off>0; off>>=1){
    sat  += __shfl_down(sat, off);
    leak += __shfl_down(leak, off);
  }
  __shared__ float red[2][4];
  int wid = tid >> 6;
  if ((tid&63)==0){ red[0][wid]=sat; red[1][wid]=leak; }
  __syncthreads();
  if (tid==0){
    atomicAdd(&accum[18], red[0][0]+red[0][1]+red[0][2]+red[0][3]);
    atomicAdd(&accum[19], red[1][0]+red[1][1]+red[1][2]+red[1][3]);
  }
}

__global__ void k_final(const float2* __restrict__ S, const int* __restrict__ target,
                        const float* __restrict__ accum, float* __restrict__ out){
  int t = threadIdx.x;
  if (t < 8){
    int ty = target[2*t], tx = target[2*t+1];
    int p = (t<<16) + (ty<<8) + tx;
    float2 c = S[p];
    float vr = c.x, vi = c.y;
    float mag = sqrtf(vr*vr+vi*vi+1e-8f);
    out[t*9] = (0.35f - mag)*12.0f;
    #pragma unroll
    for (int k=0;k<8;k++){
      float th = 6.283185307179586f * (float)k / 8.0f;
      out[t*9+1+k] = (vr*cosf(th)+vi*sinf(th) - 0.35f)*12.0f;
    }
  }
  if (t == 8){
    float d = 0.0f;
    for (int s=0;s<16;s++) d += sqrtf(accum[s]/1048576.0f);
    out[72] = d/16.0f;
    out[73] = accum[16]/8912896.0f;
    out[74] = accum[18]/1048576.0f;
    out[75] = accum[17]/(524288.0f*16.0f);
    out[76] = accum[19]/524288.0f;
  }
}

extern "C" void kernel_launch(void* const* d_in, const int* in_sizes, int n_in,
                              void* d_out, int out_size, void* d_ws, size_t ws_size,
                              hipStream_t stream) {
  const float* x       = (const float*)d_in[0];
  const int*   target  = (const int*)  d_in[1];
  const float* w_in    = (const float*)d_in[2];
  const float* b_in    = (const float*)d_in[3];
  const float* w_up    = (const float*)d_in[4];
  const float* b_up    = (const float*)d_in[5];
  const float* w_gate  = (const float*)d_in[6];
  const float* b_gate  = (const float*)d_in[7];
  const float* angle   = (const float*)d_in[8];
  const float* decay_l = (const float*)d_in[9];
  float* out = (float*)d_out;

  char* ws = (char*)d_ws;
  size_t off = 0;
  unsigned char* HH0 = (unsigned char*)(ws+off); off += (size_t)NB*PP*32;
  unsigned char* HH1 = (unsigned char*)(ws+off); off += (size_t)NB*PP*32;
  bf16* TAIL0=(bf16*)(ws+off); off += (size_t)NB*PP*32;
  bf16* TAIL1=(bf16*)(ws+off); off += (size_t)NB*PP*32;
  float2* S0 = (float2*)(ws+off); off += (size_t)NPIX*8;
  float2* S1 = (float2*)(ws+off); off += (size_t)NPIX*8;
  float2* F0 = (float2*)(ws+off); off += (size_t)NPIX*8;
  float2* F1 = (float2*)(ws+off); off += (size_t)NPIX*8;
  float* WALL = (float*)(ws+off); off += (size_t)NPIX*4;
  u64* WB8 = (u64*)(ws+off); off += (size_t)19*64*8;
  short8* WB16 = (short8*)(ws+off); off += (size_t)11*64*16;
  float* accum = (float*)(ws+off); off += 32*4;

  k_prep<<<1,32,0,stream>>>(angle, decay_l, accum);
  k_wprep<<<1,256,0,stream>>>(w_up, w_gate, WB8, WB16);
  k_border<<<(NB*PP+255)/256,256,0,stream>>>(HH0, HH1, TAIL0, TAIL1);
  k_init<<<NPIX/256,256,0,stream>>>(x, w_in, b_in, S0, F0, WALL, HH0, TAIL0, TAIL1, accum);

  unsigned char *hho=HH0, *hhn=HH1;
  bf16 *tlo=TAIL0, *tln=TAIL1;
  float2 *so=S0, *sn=S1, *fo=F0, *fn=F1;
  for (int t=1;t<=NSTEPS;t++){
    k_step<<<2048,256,0,stream>>>(hho, hhn, tlo, tln, so, sn, fo, fn, WALL,
                                  WB8, WB16, b_up, x, b_gate, accum, t);
    unsigned char* tc=hho; hho=hhn; hhn=tc;
    bf16* tb=tlo; tlo=tln; tln=tb;
    float2* tf=so; so=sn; sn=tf;
    tf=fo; fo=fn; fn=tf;
  }
  k_tail<<<NPIX/256,256,0,stream>>>(WALL, so, accum);
  k_final<<<1,64,0,stream>>>(so, target, accum, out);
}